// Round 1
// baseline (779.139 us; speedup 1.0000x reference)
//
#include <hip/hip_runtime.h>
#include <hip/hip_bf16.h>

// Problem constants
#define B_    128
#define G_    10000
#define KW_   20
#define C_    3
#define LAT_  2000
#define GC_   30000      // G*C
#define INLEN_ 200000    // N_LOCI*2

typedef short bf16x8 __attribute__((ext_vector_type(8)));
typedef float f32x4  __attribute__((ext_vector_type(4)));

__device__ __forceinline__ float leaky(float x) { return x >= 0.f ? x : 0.1f * x; }

__device__ __forceinline__ unsigned short f2bf(float f) {
    union { float f; unsigned u; } v; v.f = f;
    unsigned r = v.u + 0x7fffu + ((v.u >> 16) & 1u);   // round-to-nearest-even
    return (unsigned short)(r >> 16);
}
__device__ __forceinline__ float bf2f(unsigned short u) {
    union { unsigned u; float f; } v; v.u = ((unsigned)u) << 16; return v.f;
}

// ---------------------------------------------------------------------------
// Kernel 1: encoder grouped conv.  h[b, g*3+c] = leaky(sum_k x[b,g*20+k]*w[g,c,k] + b[g,c])
// One thread per (b, g). x staged via LDS for coalescing. h stored bf16.
// ---------------------------------------------------------------------------
__global__ __launch_bounds__(256) void k_enc(const float* __restrict__ x,
                                             const float* __restrict__ w,
                                             const float* __restrict__ bias,
                                             unsigned short* __restrict__ h) {
    __shared__ float xs[5120];                 // 256 groups * 20 floats = 20 KB
    const int t = threadIdx.x;
    const int g0 = blockIdx.x * 256;
    const int b  = blockIdx.y;

    const float* xrow = x + (size_t)b * INLEN_ + g0 * KW_;
    const int remain = INLEN_ - g0 * KW_;      // >= 320
    float4* xs4 = (float4*)xs;
    #pragma unroll
    for (int j = 0; j < 5; ++j) {
        int idx = j * 256 + t;                 // float4 index
        float4 v = make_float4(0.f, 0.f, 0.f, 0.f);
        if (idx * 4 + 3 < remain) v = ((const float4*)xrow)[idx];
        xs4[idx] = v;
    }
    __syncthreads();

    const int g = g0 + t;
    if (g >= G_) return;

    // load 60 weights (15 aligned float4)
    float wl[60];
    const float4* w4 = (const float4*)(w + (size_t)g * 60);
    #pragma unroll
    for (int i = 0; i < 15; ++i) {
        float4 v = w4[i];
        wl[4*i] = v.x; wl[4*i+1] = v.y; wl[4*i+2] = v.z; wl[4*i+3] = v.w;
    }
    float xr[20];
    const float4* xl4 = (const float4*)(xs + t * KW_);
    #pragma unroll
    for (int i = 0; i < 5; ++i) {
        float4 v = xl4[i];
        xr[4*i] = v.x; xr[4*i+1] = v.y; xr[4*i+2] = v.z; xr[4*i+3] = v.w;
    }
    unsigned short* hp = h + (size_t)b * GC_ + g * C_;
    #pragma unroll
    for (int c = 0; c < C_; ++c) {
        float s = bias[g * C_ + c];
        #pragma unroll
        for (int k = 0; k < KW_; ++k) s += xr[k] * wl[c * KW_ + k];
        hp[c] = f2bf(leaky(s));
    }
}

// ---------------------------------------------------------------------------
// FC GEMM:  C[m,n] = sum_k A[m,k] * W[n,k]    (M=128 fixed)
// Block tile 128x64, BK=32, 4 waves (2x2 of 64x32 wave tiles), mfma 16x16x32 bf16.
// A is bf16 in global; W is fp32 in global, converted to bf16 during LDS staging.
// MODE 0: write fp32 partial (split-K chunk blockIdx.y) to outp.
// MODE 1: out = bf16( leaky(C + bias[n]) ) to outb.
// ---------------------------------------------------------------------------
template <int MODE>
__global__ __launch_bounds__(256) void k_fc(const unsigned short* __restrict__ A,
                                            const float* __restrict__ W,
                                            const float* __restrict__ bias,
                                            float* __restrict__ outp,
                                            unsigned short* __restrict__ outb,
                                            int N, int K, int KC) {
    __shared__ unsigned short As[128][40];     // 40 = 32 + 8 pad (keeps 16B align, 20-bank stride)
    __shared__ unsigned short Ws[64][40];

    const int t  = threadIdx.x;
    const int n0 = blockIdx.x * 64;
    const int kb = blockIdx.y * KC;
    const int ke = min(K, kb + KC);
    const int iters = (ke - kb + 31) >> 5;

    const int ar = t >> 1,  ah = (t & 1) * 16;   // A staging: row, k-sub (16 bf16 each)
    const int wr = t >> 2,  wq = (t & 3) * 8;    // W staging: row, k-sub (8 floats each)
    const unsigned short* Ag = A + (size_t)ar * K;
    const float* Wg = W + (size_t)(n0 + wr) * K;
    const bool wvalid = (n0 + wr) < N;

    const int wave = t >> 6, lane = t & 63, quad = lane >> 4, l16 = lane & 15;
    const int wm = (wave & 1) * 64, wn = (wave >> 1) * 32;

    f32x4 acc[4][2];
    #pragma unroll
    for (int i = 0; i < 4; ++i)
        #pragma unroll
        for (int j = 0; j < 2; ++j) acc[i][j] = (f32x4){0.f, 0.f, 0.f, 0.f};

    for (int it = 0; it < iters; ++it) {
        const int k0 = kb + it * 32;
        // ---- stage A (128x32 bf16 = 8 KB) ----
        if (k0 + ah + 15 < ke) {
            const uint4* p = (const uint4*)(Ag + k0 + ah);
            *(uint4*)&As[ar][ah]     = p[0];
            *(uint4*)&As[ar][ah + 8] = p[1];
        } else {
            for (int j = 0; j < 16; ++j) {
                int k = k0 + ah + j;
                As[ar][ah + j] = (k < ke) ? Ag[k] : (unsigned short)0;
            }
        }
        // ---- stage W (64x32 fp32 -> bf16 = 4 KB) ----
        if (wvalid && (k0 + wq + 7 < ke)) {
            const float4* wp = (const float4*)(Wg + k0 + wq);
            float4 a0 = wp[0], a1 = wp[1];
            unsigned short u[8];
            u[0]=f2bf(a0.x); u[1]=f2bf(a0.y); u[2]=f2bf(a0.z); u[3]=f2bf(a0.w);
            u[4]=f2bf(a1.x); u[5]=f2bf(a1.y); u[6]=f2bf(a1.z); u[7]=f2bf(a1.w);
            *(uint4*)&Ws[wr][wq] = *(uint4*)u;
        } else {
            for (int j = 0; j < 8; ++j) {
                int k = k0 + wq + j;
                Ws[wr][wq + j] = (wvalid && k < ke) ? f2bf(Wg[k]) : (unsigned short)0;
            }
        }
        __syncthreads();
        // ---- MFMA: wave tile 64x32 = 4m x 2n of 16x16 ----
        bf16x8 af[4], bfr[2];
        #pragma unroll
        for (int mi = 0; mi < 4; ++mi)
            af[mi] = *(const bf16x8*)&As[wm + mi * 16 + l16][quad * 8];
        #pragma unroll
        for (int ni = 0; ni < 2; ++ni)
            bfr[ni] = *(const bf16x8*)&Ws[wn + ni * 16 + l16][quad * 8];
        #pragma unroll
        for (int mi = 0; mi < 4; ++mi)
            #pragma unroll
            for (int ni = 0; ni < 2; ++ni)
                acc[mi][ni] = __builtin_amdgcn_mfma_f32_16x16x32_bf16(
                    af[mi], bfr[ni], acc[mi][ni], 0, 0, 0);
        __syncthreads();
    }

    // ---- epilogue: D[row=quad*4+r][col=l16] per 16x16 tile ----
    #pragma unroll
    for (int mi = 0; mi < 4; ++mi) {
        const int row = wm + mi * 16 + quad * 4;
        #pragma unroll
        for (int ni = 0; ni < 2; ++ni) {
            const int col = n0 + wn + ni * 16 + l16;
            if (col < N) {
                if (MODE == 0) {
                    float* op = outp + (size_t)blockIdx.y * 128 * N;
                    #pragma unroll
                    for (int r = 0; r < 4; ++r)
                        op[(size_t)(row + r) * N + col] = acc[mi][ni][r];
                } else {
                    const float bv = bias[col];
                    #pragma unroll
                    for (int r = 0; r < 4; ++r)
                        outb[(size_t)(row + r) * N + col] = f2bf(leaky(acc[mi][ni][r] + bv));
                }
            }
        }
    }
}

// ---------------------------------------------------------------------------
// Kernel 3: reduce split-K partials + bias + leaky -> z bf16 [128 x 2000]
// ---------------------------------------------------------------------------
__global__ __launch_bounds__(256) void k_red(const float* __restrict__ zp,
                                             const float* __restrict__ bias,
                                             unsigned short* __restrict__ z) {
    const int i = blockIdx.x * 256 + threadIdx.x;   // < 128*2000
    float s = bias[i % LAT_];
    #pragma unroll
    for (int c = 0; c < 8; ++c) s += zp[(size_t)c * 128 * LAT_ + i];
    z[i] = f2bf(leaky(s));
}

// ---------------------------------------------------------------------------
// Kernel 5: decoder conv-transpose + sigmoid.
// out[b, g*20+k] = sigmoid(dec_b[g] + sum_c d[b,g*3+c]*w[g,c,k])
// ---------------------------------------------------------------------------
__global__ __launch_bounds__(256) void k_dec(const unsigned short* __restrict__ d,
                                             const float* __restrict__ w,
                                             const float* __restrict__ bias,
                                             float* __restrict__ out) {
    const int t = threadIdx.x;
    const int g = blockIdx.x * 256 + t;
    const int b = blockIdx.y;
    if (g >= G_) return;

    const unsigned short* dp = d + (size_t)b * GC_ + g * C_;
    float dv0 = bf2f(dp[0]), dv1 = bf2f(dp[1]), dv2 = bf2f(dp[2]);

    float wl[60];
    const float4* w4 = (const float4*)(w + (size_t)g * 60);
    #pragma unroll
    for (int i = 0; i < 15; ++i) {
        float4 v = w4[i];
        wl[4*i] = v.x; wl[4*i+1] = v.y; wl[4*i+2] = v.z; wl[4*i+3] = v.w;
    }
    const float bg = bias[g];
    float o[20];
    #pragma unroll
    for (int k = 0; k < KW_; ++k) {
        float s = bg + dv0 * wl[k] + dv1 * wl[20 + k] + dv2 * wl[40 + k];
        o[k] = 1.f / (1.f + __expf(-s));
    }
    float4* op = (float4*)(out + (size_t)b * INLEN_ + g * KW_);
    #pragma unroll
    for (int i = 0; i < 5; ++i)
        op[i] = make_float4(o[4*i], o[4*i+1], o[4*i+2], o[4*i+3]);
}

// ---------------------------------------------------------------------------
extern "C" void kernel_launch(void* const* d_in, const int* in_sizes, int n_in,
                              void* d_out, int out_size, void* d_ws, size_t ws_size,
                              hipStream_t stream) {
    const float* x        = (const float*)d_in[0];
    const float* enc_w    = (const float*)d_in[1];
    const float* enc_b    = (const float*)d_in[2];
    const float* enc_fc_w = (const float*)d_in[3];
    const float* enc_fc_b = (const float*)d_in[4];
    const float* dec_fc_w = (const float*)d_in[5];
    const float* dec_fc_b = (const float*)d_in[6];
    const float* dec_w    = (const float*)d_in[7];
    const float* dec_b    = (const float*)d_in[8];
    float* out = (float*)d_out;

    // workspace layout (~24.1 MB total)
    char* ws = (char*)d_ws;
    unsigned short* h  = (unsigned short*)ws;              //  7,680,000 B : h bf16 [128][30000]
    float*          zp = (float*)(ws + 7680000);           //  8,192,000 B : z partials [8][128][2000]
    unsigned short* z  = (unsigned short*)(ws + 15872000); //    512,000 B : z bf16 [128][2000]
    unsigned short* dd = (unsigned short*)(ws + 16384000); //  7,680,000 B : d bf16 [128][30000]

    k_enc<<<dim3(40, 128), 256, 0, stream>>>(x, enc_w, enc_b, h);
    // FC1: N=2000 (32 n-tiles), K=30000 split into 8 chunks of 3776 (32-aligned)
    k_fc<0><<<dim3(32, 8), 256, 0, stream>>>(h, enc_fc_w, nullptr, zp, nullptr, LAT_, GC_, 3776);
    k_red<<<dim3(1000), 256, 0, stream>>>(zp, enc_fc_b, z);
    // FC2: N=30000 (469 n-tiles), K=2000 single chunk
    k_fc<1><<<dim3(469, 1), 256, 0, stream>>>(z, dec_fc_w, dec_fc_b, nullptr, dd, GC_, LAT_, LAT_);
    k_dec<<<dim3(40, 128), 256, 0, stream>>>(dd, dec_w, dec_b, out);
}